// Round 4
// baseline (150.362 us; speedup 1.0000x reference)
//
#include <hip/hip_runtime.h>

typedef __attribute__((ext_vector_type(8))) short short8;
typedef __attribute__((ext_vector_type(4))) short short4v;
typedef __attribute__((ext_vector_type(4))) float floatx4;

#define D 128
#define NWAVES 4
#define GRID_MLP 512
#define TSTRIDE (GRID_MLP * NWAVES)
#define EDGE_BLOCKS 1024

__device__ __forceinline__ unsigned short f2bf(float f) {
  unsigned u = __float_as_uint(f);
  u += 0x7FFFu + ((u >> 16) & 1u);   // RNE
  return (unsigned short)(u >> 16);
}

// W transposed+swizzled in LDS: element (n,k) at n*128 + (((k>>3)^(n&15))<<3) + (k&7)
// -> B-frag ds_read_b128 conflict-free.
__device__ __forceinline__ void stageW(const float* __restrict__ W,
                                       unsigned short* __restrict__ sW, int tid) {
  const int n = tid & 127;
  const int tg = tid >> 7;
  #pragma unroll
  for (int iter = 0; iter < 16; ++iter) {
    const int k0 = iter * 8 + tg * 4;
    float w0 = W[(k0 + 0) * D + n];
    float w1 = W[(k0 + 1) * D + n];
    float w2 = W[(k0 + 2) * D + n];
    float w3 = W[(k0 + 3) * D + n];
    short4v p;
    p[0] = (short)f2bf(w0); p[1] = (short)f2bf(w1);
    p[2] = (short)f2bf(w2); p[3] = (short)f2bf(w3);
    const int idx = n * D + (((k0 >> 3) ^ (n & 15)) << 3) + (k0 & 7);
    *(short4v*)&sW[idx] = p;
  }
}

__device__ __forceinline__ void load_x(const float* __restrict__ x, int t, int l16,
                                       int quad, int nNodes, float4 xf[8]) {
  const int m = t * 16 + l16;
  if (m < nNodes) {
    const float* xp = x + (size_t)m * D + quad * 8;
    #pragma unroll
    for (int kk = 0; kk < 4; ++kk) {
      xf[2 * kk]     = *(const float4*)(xp + kk * 32);
      xf[2 * kk + 1] = *(const float4*)(xp + kk * 32 + 4);
    }
  } else {
    #pragma unroll
    for (int i = 0; i < 8; ++i) xf[i] = make_float4(0.f, 0.f, 0.f, 0.f);
  }
}

__device__ __forceinline__ void process_tile(
    const float4 xf[8], int t, const unsigned short* __restrict__ sW1,
    const unsigned short* __restrict__ sW2, unsigned short* __restrict__ mysH,
    const float bias1[8], const float bias2[8], unsigned short* __restrict__ h,
    int nNodes, int quad, int l16) {
  // ---- layer 1 ----
  floatx4 acc[8];
  #pragma unroll
  for (int n0 = 0; n0 < 8; ++n0) acc[n0] = (floatx4){0.f, 0.f, 0.f, 0.f};
  #pragma unroll
  for (int kk = 0; kk < 4; ++kk) {
    const float4 f0 = xf[2 * kk], f1 = xf[2 * kk + 1];
    short8 a;
    a[0] = (short)f2bf(f0.x); a[1] = (short)f2bf(f0.y);
    a[2] = (short)f2bf(f0.z); a[3] = (short)f2bf(f0.w);
    a[4] = (short)f2bf(f1.x); a[5] = (short)f2bf(f1.y);
    a[6] = (short)f2bf(f1.z); a[7] = (short)f2bf(f1.w);
    #pragma unroll
    for (int n0 = 0; n0 < 8; ++n0) {
      short8 b = *(const short8*)&sW1[(n0 * 16 + l16) * D + (((kk * 4 + quad) ^ l16) << 3)];
      acc[n0] = __builtin_amdgcn_mfma_f32_16x16x32_bf16(a, b, acc[n0], 0, 0, 0);
    }
  }
  // epilogue 1 -> per-wave swizzled sH
  #pragma unroll
  for (int n0 = 0; n0 < 8; ++n0) {
    #pragma unroll
    for (int r = 0; r < 4; ++r) {
      float v = acc[n0][r] + bias1[n0];
      v = v > 0.f ? v : 0.f;
      const int row = quad * 4 + r;
      const int g = 2 * n0 + (l16 >> 3);
      mysH[row * D + (((g ^ row) & 15) << 3) + (l16 & 7)] = f2bf(v);
    }
  }
  // h1 A-fragments
  short8 af[4];
  #pragma unroll
  for (int kk = 0; kk < 4; ++kk)
    af[kk] = *(const short8*)&mysH[l16 * D + ((((kk * 4 + quad) ^ l16) & 15) << 3)];
  // ---- layer 2 ----
  #pragma unroll
  for (int n0 = 0; n0 < 8; ++n0) acc[n0] = (floatx4){0.f, 0.f, 0.f, 0.f};
  #pragma unroll
  for (int kk = 0; kk < 4; ++kk) {
    #pragma unroll
    for (int n0 = 0; n0 < 8; ++n0) {
      short8 b = *(const short8*)&sW2[(n0 * 16 + l16) * D + (((kk * 4 + quad) ^ l16) << 3)];
      acc[n0] = __builtin_amdgcn_mfma_f32_16x16x32_bf16(af[kk], b, acc[n0], 0, 0, 0);
    }
  }
  // epilogue 2 -> sH (safe: per-wave in-order LDS)
  #pragma unroll
  for (int n0 = 0; n0 < 8; ++n0) {
    #pragma unroll
    for (int r = 0; r < 4; ++r) {
      float v = acc[n0][r] + bias2[n0];
      v = v > 0.f ? v : 0.f;
      const int row = quad * 4 + r;
      const int g = 2 * n0 + (l16 >> 3);
      mysH[row * D + (((g ^ row) & 15) << 3) + (l16 & 7)] = f2bf(v);
    }
  }
  // coalesced row-major global stores
  #pragma unroll
  for (int i = 0; i < 4; ++i) {
    const int row = i * 4 + quad;
    short8 vrow = *(const short8*)&mysH[row * D + (((l16 ^ row) & 15) << 3)];
    const int g = t * 16 + row;
    if (g < nNodes) *(short8*)&h[(size_t)g * D + l16 * 8] = vrow;
  }
}

// Fused 2-layer MLP, software-pipelined x prefetch (2-deep).
__global__ __launch_bounds__(256) void mlp_fused(
    const float* __restrict__ x, const float* __restrict__ W1,
    const float* __restrict__ b1, const float* __restrict__ W2,
    const float* __restrict__ b2, unsigned short* __restrict__ h,
    const int* __restrict__ elabel, float* __restrict__ out,
    int nNodes, int ntiles, int E) {
  __shared__ unsigned short sW1[D * D];
  __shared__ unsigned short sW2[D * D];
  __shared__ unsigned short sH[NWAVES][16 * D];
  const int tid = threadIdx.x;
  const int wave = tid >> 6, lane = tid & 63;
  const int quad = lane >> 4, l16 = lane & 15;

  // labels: vectorized int4 -> float4
  {
    const int E4 = E & ~3;
    for (int li = (blockIdx.x * 256 + tid) * 4; li < E4; li += GRID_MLP * 256 * 4) {
      int4 lv = *(const int4*)&elabel[li];
      float4 fv = make_float4((float)lv.x, (float)lv.y, (float)lv.z, (float)lv.w);
      *(float4*)&out[E + li] = fv;
    }
    if (blockIdx.x == 0 && tid < (E & 3)) out[E + E4 + tid] = (float)elabel[E4 + tid];
  }

  stageW(W1, sW1, tid);
  stageW(W2, sW2, tid);
  __syncthreads();

  float bias1[8], bias2[8];
  #pragma unroll
  for (int n0 = 0; n0 < 8; ++n0) { bias1[n0] = b1[n0 * 16 + l16]; bias2[n0] = b2[n0 * 16 + l16]; }

  unsigned short* mysH = sH[wave];

  float4 xfA[8], xfB[8];
  int t = blockIdx.x * NWAVES + wave;
  if (t < ntiles) {
    load_x(x, t, l16, quad, nNodes, xfA);
    while (true) {
      int t2 = t + TSTRIDE;
      if (t2 < ntiles) {
        load_x(x, t2, l16, quad, nNodes, xfB);
        process_tile(xfA, t, sW1, sW2, mysH, bias1, bias2, h, nNodes, quad, l16);
        t = t2;
      } else {
        process_tile(xfA, t, sW1, sW2, mysH, bias1, bias2, h, nNodes, quad, l16);
        break;
      }
      int t3 = t + TSTRIDE;
      if (t3 < ntiles) {
        load_x(x, t3, l16, quad, nNodes, xfA);
        process_tile(xfB, t, sW1, sW2, mysH, bias1, bias2, h, nNodes, quad, l16);
        t = t3;
      } else {
        process_tile(xfB, t, sW1, sW2, mysH, bias1, bias2, h, nNodes, quad, l16);
        break;
      }
    }
  }
}

__device__ __forceinline__ float dot2bf(unsigned a, unsigned b, float acc) {
  float a0 = __uint_as_float(a << 16);
  float a1 = __uint_as_float(a & 0xFFFF0000u);
  float b0 = __uint_as_float(b << 16);
  float b1 = __uint_as_float(b & 0xFFFF0000u);
  acc = fmaf(a0, b0, acc);
  acc = fmaf(a1, b1, acc);
  return acc;
}

__device__ __forceinline__ float edge_dot(const uint4& a, const uint4& b) {
  float acc = 0.f;
  acc = dot2bf(a.x, b.x, acc);
  acc = dot2bf(a.y, b.y, acc);
  acc = dot2bf(a.z, b.z, acc);
  acc = dot2bf(a.w, b.w, acc);
  acc += __shfl_xor(acc, 8);
  acc += __shfl_xor(acc, 4);
  acc += __shfl_xor(acc, 2);
  acc += __shfl_xor(acc, 1);
  return acc;
}

__device__ __forceinline__ void edge_load(const unsigned short* __restrict__ h2,
                                          const int* __restrict__ eidx, int E,
                                          int q, int sub, uint4 va[4], uint4 vb[4]) {
  const int e0 = q * 4;
  const int4 s = *(const int4*)&eidx[e0];
  const int4 d = *(const int4*)&eidx[E + e0];
  const size_t off = (size_t)(sub * 8);
  va[0] = *(const uint4*)(h2 + (((size_t)(unsigned)s.x) << 7) + off);
  va[1] = *(const uint4*)(h2 + (((size_t)(unsigned)s.y) << 7) + off);
  va[2] = *(const uint4*)(h2 + (((size_t)(unsigned)s.z) << 7) + off);
  va[3] = *(const uint4*)(h2 + (((size_t)(unsigned)s.w) << 7) + off);
  vb[0] = *(const uint4*)(h2 + (((size_t)(unsigned)d.x) << 7) + off);
  vb[1] = *(const uint4*)(h2 + (((size_t)(unsigned)d.y) << 7) + off);
  vb[2] = *(const uint4*)(h2 + (((size_t)(unsigned)d.z) << 7) + off);
  vb[3] = *(const uint4*)(h2 + (((size_t)(unsigned)d.w) << 7) + off);
}

__device__ __forceinline__ void edge_compute(const uint4 va[4], const uint4 vb[4],
                                             int q, int sub, float* __restrict__ out) {
  #pragma unroll
  for (int i = 0; i < 4; ++i) {
    float acc = edge_dot(va[i], vb[i]);
    if (sub == 0) out[q * 4 + i] = acc;
  }
}

// Edge decode: persistent grid, 16 lanes/edge, 4 edges/batch, 2-deep reg pipeline.
__global__ __launch_bounds__(256) void edge_kernel(
    const unsigned short* __restrict__ h2, const int* __restrict__ eidx,
    float* __restrict__ out, int E) {
  const int sub = threadIdx.x & 15;
  const int grp = (blockIdx.x * 256 + threadIdx.x) >> 4;
  const int ngrp = (EDGE_BLOCKS * 256) >> 4;
  const int nq = E >> 2;

  uint4 vaA[4], vbA[4], vaB[4], vbB[4];
  int q = grp;
  if (q < nq) {
    edge_load(h2, eidx, E, q, sub, vaA, vbA);
    while (true) {
      int q2 = q + ngrp;
      if (q2 < nq) {
        edge_load(h2, eidx, E, q2, sub, vaB, vbB);
        edge_compute(vaA, vbA, q, sub, out);
        q = q2;
      } else {
        edge_compute(vaA, vbA, q, sub, out);
        break;
      }
      int q3 = q + ngrp;
      if (q3 < nq) {
        edge_load(h2, eidx, E, q3, sub, vaA, vbA);
        edge_compute(vaB, vbB, q, sub, out);
        q = q3;
      } else {
        edge_compute(vaB, vbB, q, sub, out);
        break;
      }
    }
  }
  // tail (E % 4 != 0): one group handles it
  if (grp == ngrp - 1) {
    for (int e = nq * 4; e < E; ++e) {
      const int s = eidx[e];
      const int d = eidx[E + e];
      const uint4 ua = *(const uint4*)(h2 + (((size_t)(unsigned)s) << 7) + sub * 8);
      const uint4 ub = *(const uint4*)(h2 + (((size_t)(unsigned)d) << 7) + sub * 8);
      float acc = edge_dot(ua, ub);
      if (sub == 0) out[e] = acc;
    }
  }
}

extern "C" void kernel_launch(void* const* d_in, const int* in_sizes, int n_in,
                              void* d_out, int out_size, void* d_ws, size_t ws_size,
                              hipStream_t stream) {
  const float* x  = (const float*)d_in[0];
  const int* eidx = (const int*)d_in[1];
  const int* elab = (const int*)d_in[2];
  const float* W1 = (const float*)d_in[3];
  const float* b1 = (const float*)d_in[4];
  const float* W2 = (const float*)d_in[5];
  const float* b2 = (const float*)d_in[6];
  float* out = (float*)d_out;

  const int nNodes = in_sizes[0] / D;   // 100000
  const int E = in_sizes[2];            // 500000
  const int ntiles = (nNodes + 15) / 16;

  unsigned short* h = (unsigned short*)d_ws;  // nNodes*128 bf16 = 25.6 MB

  mlp_fused<<<GRID_MLP, 256, 0, stream>>>(x, W1, b1, W2, b2, h, elab, out,
                                          nNodes, ntiles, E);
  edge_kernel<<<EDGE_BLOCKS, 256, 0, stream>>>(h, eidx, out, E);
}

// Round 6
// 146.349 us; speedup vs baseline: 1.0274x; 1.0274x over previous
//
#include <hip/hip_runtime.h>

typedef __attribute__((ext_vector_type(8))) short short8;
typedef __attribute__((ext_vector_type(4))) short short4v;
typedef __attribute__((ext_vector_type(4))) float floatx4;

#define D 128
#define NWAVES 4
#define GRID_MLP 512

__device__ __forceinline__ unsigned short f2bf(float f) {
  unsigned u = __float_as_uint(f);
  u += 0x7FFFu + ((u >> 16) & 1u);   // RNE
  return (unsigned short)(u >> 16);
}

// W transposed+swizzled in LDS: element (n,k) at n*128 + (((k>>3)^(n&15))<<3) + (k&7)
// -> B-frag ds_read_b128 conflict-free.
__device__ __forceinline__ void stageW(const float* __restrict__ W,
                                       unsigned short* __restrict__ sW, int tid) {
  const int n = tid & 127;
  const int tg = tid >> 7;
  #pragma unroll
  for (int iter = 0; iter < 16; ++iter) {
    const int k0 = iter * 8 + tg * 4;
    float w0 = W[(k0 + 0) * D + n];
    float w1 = W[(k0 + 1) * D + n];
    float w2 = W[(k0 + 2) * D + n];
    float w3 = W[(k0 + 3) * D + n];
    short4v p;
    p[0] = (short)f2bf(w0); p[1] = (short)f2bf(w1);
    p[2] = (short)f2bf(w2); p[3] = (short)f2bf(w3);
    const int idx = n * D + (((k0 >> 3) ^ (n & 15)) << 3) + (k0 & 7);
    *(short4v*)&sW[idx] = p;
  }
}

// Fused 2-layer MLP: h2 = relu(relu(x@W1+b1)@W2+b2), fp32 in, bf16 out.
// h1 stays in a per-wave XOR-swizzled LDS transpose buffer (no global round-trip).
// x read nontemporal (streamed once; don't thrash L2).
__global__ __launch_bounds__(256) void mlp_fused(
    const float* __restrict__ x, const float* __restrict__ W1,
    const float* __restrict__ b1, const float* __restrict__ W2,
    const float* __restrict__ b2, unsigned short* __restrict__ h,
    const int* __restrict__ elabel, float* __restrict__ out,
    int nNodes, int ntiles, int E) {
  __shared__ unsigned short sW1[D * D];          // 32 KB
  __shared__ unsigned short sW2[D * D];          // 32 KB
  __shared__ unsigned short sH[NWAVES][16 * D];  // 16 KB
  const int tid = threadIdx.x;
  const int wave = tid >> 6, lane = tid & 63;
  const int quad = lane >> 4, l16 = lane & 15;

  // labels: vectorized int4 -> float4, overlapped with W staging
  {
    const int E4 = E & ~3;
    for (int li = (blockIdx.x * 256 + tid) * 4; li < E4; li += GRID_MLP * 256 * 4) {
      int4 lv = *(const int4*)&elabel[li];
      float4 fv = make_float4((float)lv.x, (float)lv.y, (float)lv.z, (float)lv.w);
      *(float4*)&out[E + li] = fv;
    }
    if (blockIdx.x == 0 && tid < (E & 3)) out[E + E4 + tid] = (float)elabel[E4 + tid];
  }

  stageW(W1, sW1, tid);
  stageW(W2, sW2, tid);
  __syncthreads();

  float bias1[8], bias2[8];
  #pragma unroll
  for (int n0 = 0; n0 < 8; ++n0) { bias1[n0] = b1[n0 * 16 + l16]; bias2[n0] = b2[n0 * 16 + l16]; }

  unsigned short* mysH = sH[wave];

  for (int t = blockIdx.x * NWAVES + wave; t < ntiles; t += GRID_MLP * NWAVES) {
    const int m = t * 16 + l16;
    const bool mv = (m < nNodes);
    floatx4 xf[8];
    const floatx4* xp = (const floatx4*)(x + (size_t)m * D + quad * 8);
    #pragma unroll
    for (int kk = 0; kk < 4; ++kk) {
      if (mv) {
        xf[2 * kk]     = __builtin_nontemporal_load(xp + kk * 8);
        xf[2 * kk + 1] = __builtin_nontemporal_load(xp + kk * 8 + 1);
      } else {
        xf[2 * kk] = (floatx4){0.f, 0.f, 0.f, 0.f};
        xf[2 * kk + 1] = (floatx4){0.f, 0.f, 0.f, 0.f};
      }
    }
    // ---- layer 1 ----
    floatx4 acc[8];
    #pragma unroll
    for (int n0 = 0; n0 < 8; ++n0) acc[n0] = (floatx4){0.f, 0.f, 0.f, 0.f};
    #pragma unroll
    for (int kk = 0; kk < 4; ++kk) {
      const floatx4 f0 = xf[2 * kk], f1 = xf[2 * kk + 1];
      short8 a;
      a[0] = (short)f2bf(f0[0]); a[1] = (short)f2bf(f0[1]);
      a[2] = (short)f2bf(f0[2]); a[3] = (short)f2bf(f0[3]);
      a[4] = (short)f2bf(f1[0]); a[5] = (short)f2bf(f1[1]);
      a[6] = (short)f2bf(f1[2]); a[7] = (short)f2bf(f1[3]);
      #pragma unroll
      for (int n0 = 0; n0 < 8; ++n0) {
        short8 b = *(const short8*)&sW1[(n0 * 16 + l16) * D + (((kk * 4 + quad) ^ l16) << 3)];
        acc[n0] = __builtin_amdgcn_mfma_f32_16x16x32_bf16(a, b, acc[n0], 0, 0, 0);
      }
    }
    // epilogue 1: bias+relu -> per-wave swizzled sH (C/D layout scatter)
    #pragma unroll
    for (int n0 = 0; n0 < 8; ++n0) {
      #pragma unroll
      for (int r = 0; r < 4; ++r) {
        float v = acc[n0][r] + bias1[n0];
        v = v > 0.f ? v : 0.f;
        const int row = quad * 4 + r;
        const int g = 2 * n0 + (l16 >> 3);
        mysH[row * D + (((g ^ row) & 15) << 3) + (l16 & 7)] = f2bf(v);
      }
    }
    // h1 A-fragments (conflict-free swizzled b128 reads)
    short8 af[4];
    #pragma unroll
    for (int kk = 0; kk < 4; ++kk)
      af[kk] = *(const short8*)&mysH[l16 * D + ((((kk * 4 + quad) ^ l16) & 15) << 3)];
    // ---- layer 2 ----
    #pragma unroll
    for (int n0 = 0; n0 < 8; ++n0) acc[n0] = (floatx4){0.f, 0.f, 0.f, 0.f};
    #pragma unroll
    for (int kk = 0; kk < 4; ++kk) {
      #pragma unroll
      for (int n0 = 0; n0 < 8; ++n0) {
        short8 b = *(const short8*)&sW2[(n0 * 16 + l16) * D + (((kk * 4 + quad) ^ l16) << 3)];
        acc[n0] = __builtin_amdgcn_mfma_f32_16x16x32_bf16(af[kk], b, acc[n0], 0, 0, 0);
      }
    }
    // epilogue 2: bias+relu -> sH (safe overwrite: per-wave in-order LDS)
    #pragma unroll
    for (int n0 = 0; n0 < 8; ++n0) {
      #pragma unroll
      for (int r = 0; r < 4; ++r) {
        float v = acc[n0][r] + bias2[n0];
        v = v > 0.f ? v : 0.f;
        const int row = quad * 4 + r;
        const int g = 2 * n0 + (l16 >> 3);
        mysH[row * D + (((g ^ row) & 15) << 3) + (l16 & 7)] = f2bf(v);
      }
    }
    // repack: coalesced row-major global stores (4 rows x 256B)
    #pragma unroll
    for (int i = 0; i < 4; ++i) {
      const int row = i * 4 + quad;
      short8 vrow = *(const short8*)&mysH[row * D + (((l16 ^ row) & 15) << 3)];
      const int g = t * 16 + row;
      if (g < nNodes) *(short8*)&h[(size_t)g * D + l16 * 8] = vrow;
    }
  }
}

__device__ __forceinline__ float dot2bf(unsigned a, unsigned b, float acc) {
  float a0 = __uint_as_float(a << 16);
  float a1 = __uint_as_float(a & 0xFFFF0000u);
  float b0 = __uint_as_float(b << 16);
  float b1 = __uint_as_float(b & 0xFFFF0000u);
  acc = fmaf(a0, b0, acc);
  acc = fmaf(a1, b1, acc);
  return acc;
}

__device__ __forceinline__ float edge_dot(const uint4& a, const uint4& b) {
  float acc = 0.f;
  acc = dot2bf(a.x, b.x, acc);
  acc = dot2bf(a.y, b.y, acc);
  acc = dot2bf(a.z, b.z, acc);
  acc = dot2bf(a.w, b.w, acc);
  acc += __shfl_xor(acc, 8);
  acc += __shfl_xor(acc, 4);
  acc += __shfl_xor(acc, 2);
  acc += __shfl_xor(acc, 1);
  return acc;
}

// Edge decode: 16 lanes/edge, 8 edges per group -> 16 gathers (256B) in flight.
// One-shot blocks (3907): block churn keeps the load pipe full.
__global__ __launch_bounds__(256) void edge_kernel(
    const unsigned short* __restrict__ h2, const int* __restrict__ eidx,
    float* __restrict__ out, int E) {
  const int sub = threadIdx.x & 15;
  const int grp = (blockIdx.x * 256 + threadIdx.x) >> 4;
  const int e0 = grp * 8;
  if (e0 + 8 <= E) {
    const int4 s0 = *(const int4*)&eidx[e0];
    const int4 s1 = *(const int4*)&eidx[e0 + 4];
    const int4 t0 = *(const int4*)&eidx[E + e0];
    const int4 t1 = *(const int4*)&eidx[E + e0 + 4];
    int s[8] = {s0.x, s0.y, s0.z, s0.w, s1.x, s1.y, s1.z, s1.w};
    int d[8] = {t0.x, t0.y, t0.z, t0.w, t1.x, t1.y, t1.z, t1.w};
    uint4 va[8], vb[8];
    #pragma unroll
    for (int i = 0; i < 8; ++i) {
      va[i] = *(const uint4*)(h2 + (((size_t)(unsigned)s[i]) << 7) + sub * 8);
      vb[i] = *(const uint4*)(h2 + (((size_t)(unsigned)d[i]) << 7) + sub * 8);
    }
    #pragma unroll
    for (int i = 0; i < 8; ++i) {
      float acc = edge_dot(va[i], vb[i]);
      if (sub == 0) out[e0 + i] = acc;
    }
  } else if (e0 < E) {
    for (int e = e0; e < E; ++e) {
      const int s = eidx[e];
      const int d = eidx[E + e];
      const uint4 ua = *(const uint4*)(h2 + (((size_t)(unsigned)s) << 7) + sub * 8);
      const uint4 ub = *(const uint4*)(h2 + (((size_t)(unsigned)d) << 7) + sub * 8);
      float acc = edge_dot(ua, ub);
      if (sub == 0) out[e] = acc;
    }
  }
}

extern "C" void kernel_launch(void* const* d_in, const int* in_sizes, int n_in,
                              void* d_out, int out_size, void* d_ws, size_t ws_size,
                              hipStream_t stream) {
  const float* x  = (const float*)d_in[0];
  const int* eidx = (const int*)d_in[1];
  const int* elab = (const int*)d_in[2];
  const float* W1 = (const float*)d_in[3];
  const float* b1 = (const float*)d_in[4];
  const float* W2 = (const float*)d_in[5];
  const float* b2 = (const float*)d_in[6];
  float* out = (float*)d_out;

  const int nNodes = in_sizes[0] / D;   // 100000
  const int E = in_sizes[2];            // 500000
  const int ntiles = (nNodes + 15) / 16;

  unsigned short* h = (unsigned short*)d_ws;  // nNodes*128 bf16 = 25.6 MB

  mlp_fused<<<GRID_MLP, 256, 0, stream>>>(x, W1, b1, W2, b2, h, elab, out,
                                          nNodes, ntiles, E);

  const int edgeBlocks = (E + 127) / 128;   // 8 edges per 16-lane group
  edge_kernel<<<edgeBlocks, 256, 0, stream>>>(h, eidx, out, E);
}

// Round 7
// 140.373 us; speedup vs baseline: 1.0712x; 1.0426x over previous
//
#include <hip/hip_runtime.h>

typedef __attribute__((ext_vector_type(8))) short short8;
typedef __attribute__((ext_vector_type(4))) short short4v;
typedef __attribute__((ext_vector_type(4))) float floatx4;

#define D 128
#define NWAVES 4
#define GRID_MLP 512

__device__ __forceinline__ unsigned short f2bf(float f) {
  unsigned u = __float_as_uint(f);
  u += 0x7FFFu + ((u >> 16) & 1u);   // RNE
  return (unsigned short)(u >> 16);
}

// W transposed+swizzled in LDS: element (n,k) at n*128 + (((k>>3)^(n&15))<<3) + (k&7)
// -> B-frag ds_read_b128 conflict-free.
__device__ __forceinline__ void stageW(const float* __restrict__ W,
                                       unsigned short* __restrict__ sW, int tid) {
  const int n = tid & 127;
  const int tg = tid >> 7;
  #pragma unroll
  for (int iter = 0; iter < 16; ++iter) {
    const int k0 = iter * 8 + tg * 4;
    float w0 = W[(k0 + 0) * D + n];
    float w1 = W[(k0 + 1) * D + n];
    float w2 = W[(k0 + 2) * D + n];
    float w3 = W[(k0 + 3) * D + n];
    short4v p;
    p[0] = (short)f2bf(w0); p[1] = (short)f2bf(w1);
    p[2] = (short)f2bf(w2); p[3] = (short)f2bf(w3);
    const int idx = n * D + (((k0 >> 3) ^ (n & 15)) << 3) + (k0 & 7);
    *(short4v*)&sW[idx] = p;
  }
}

__device__ __forceinline__ short8 cvt_a(const floatx4& f0, const floatx4& f1) {
  short8 a;
  a[0] = (short)f2bf(f0[0]); a[1] = (short)f2bf(f0[1]);
  a[2] = (short)f2bf(f0[2]); a[3] = (short)f2bf(f0[3]);
  a[4] = (short)f2bf(f1[0]); a[5] = (short)f2bf(f1[1]);
  a[6] = (short)f2bf(f1[2]); a[7] = (short)f2bf(f1[3]);
  return a;
}

// Fused 2-layer MLP, register-blocked 2x: each wave computes 32 rows per
// iteration so every B-fragment ds_read_b128 feeds TWO MFMAs.
// h1 lives in a per-wave XOR-swizzled 16x128 LDS buffer, reused sequentially
// by the two row-halves (per-wave LDS is in-order -> overwrite is safe).
__global__ __launch_bounds__(256) void mlp_fused(
    const float* __restrict__ x, const float* __restrict__ W1,
    const float* __restrict__ b1, const float* __restrict__ W2,
    const float* __restrict__ b2, unsigned short* __restrict__ h,
    const int* __restrict__ elabel, float* __restrict__ out,
    int nNodes, int npairs, int E) {
  __shared__ unsigned short sW1[D * D];          // 32 KB
  __shared__ unsigned short sW2[D * D];          // 32 KB
  __shared__ unsigned short sH[NWAVES][16 * D];  // 16 KB
  const int tid = threadIdx.x;
  const int wave = tid >> 6, lane = tid & 63;
  const int quad = lane >> 4, l16 = lane & 15;

  // labels: vectorized int4 -> float4, overlapped with W staging
  {
    const int E4 = E & ~3;
    for (int li = (blockIdx.x * 256 + tid) * 4; li < E4; li += GRID_MLP * 256 * 4) {
      int4 lv = *(const int4*)&elabel[li];
      float4 fv = make_float4((float)lv.x, (float)lv.y, (float)lv.z, (float)lv.w);
      *(float4*)&out[E + li] = fv;
    }
    if (blockIdx.x == 0 && tid < (E & 3)) out[E + E4 + tid] = (float)elabel[E4 + tid];
  }

  stageW(W1, sW1, tid);
  stageW(W2, sW2, tid);
  __syncthreads();

  float bias1[8], bias2[8];
  #pragma unroll
  for (int n0 = 0; n0 < 8; ++n0) { bias1[n0] = b1[n0 * 16 + l16]; bias2[n0] = b2[n0 * 16 + l16]; }

  unsigned short* mysH = sH[wave];

  for (int p = blockIdx.x * NWAVES + wave; p < npairs; p += GRID_MLP * NWAVES) {
    const int mbase = p * 32;
    const int m0 = mbase + l16;
    const int m1 = m0 + 16;
    floatx4 xf0[8], xf1[8];
    {
      const floatx4* xp0 = (const floatx4*)(x + (size_t)m0 * D + quad * 8);
      const floatx4* xp1 = (const floatx4*)(x + (size_t)m1 * D + quad * 8);
      const bool v0 = (m0 < nNodes), v1 = (m1 < nNodes);
      #pragma unroll
      for (int i = 0; i < 8; ++i) {
        const int o = (i >> 1) * 8 + (i & 1);
        xf0[i] = v0 ? xp0[o] : (floatx4){0.f, 0.f, 0.f, 0.f};
        xf1[i] = v1 ? xp1[o] : (floatx4){0.f, 0.f, 0.f, 0.f};
      }
    }
    // ---- layer 1 ----
    floatx4 acc0[8], acc1[8];
    #pragma unroll
    for (int n0 = 0; n0 < 8; ++n0) {
      acc0[n0] = (floatx4){0.f, 0.f, 0.f, 0.f};
      acc1[n0] = (floatx4){0.f, 0.f, 0.f, 0.f};
    }
    #pragma unroll
    for (int kk = 0; kk < 4; ++kk) {
      const short8 a0 = cvt_a(xf0[2 * kk], xf0[2 * kk + 1]);
      const short8 a1 = cvt_a(xf1[2 * kk], xf1[2 * kk + 1]);
      #pragma unroll
      for (int n0 = 0; n0 < 8; ++n0) {
        short8 b = *(const short8*)&sW1[(n0 * 16 + l16) * D + (((kk * 4 + quad) ^ l16) << 3)];
        acc0[n0] = __builtin_amdgcn_mfma_f32_16x16x32_bf16(a0, b, acc0[n0], 0, 0, 0);
        acc1[n0] = __builtin_amdgcn_mfma_f32_16x16x32_bf16(a1, b, acc1[n0], 0, 0, 0);
      }
    }
    // epilogue 1, half 0 -> sH, then read A-frags
    short8 af0[4], af1[4];
    #pragma unroll
    for (int n0 = 0; n0 < 8; ++n0) {
      #pragma unroll
      for (int r = 0; r < 4; ++r) {
        float v = acc0[n0][r] + bias1[n0];
        v = v > 0.f ? v : 0.f;
        const int row = quad * 4 + r;
        const int g = 2 * n0 + (l16 >> 3);
        mysH[row * D + (((g ^ row) & 15) << 3) + (l16 & 7)] = f2bf(v);
      }
    }
    #pragma unroll
    for (int kk = 0; kk < 4; ++kk)
      af0[kk] = *(const short8*)&mysH[l16 * D + ((((kk * 4 + quad) ^ l16) & 15) << 3)];
    // epilogue 1, half 1 -> sH (overwrite), then read A-frags
    #pragma unroll
    for (int n0 = 0; n0 < 8; ++n0) {
      #pragma unroll
      for (int r = 0; r < 4; ++r) {
        float v = acc1[n0][r] + bias1[n0];
        v = v > 0.f ? v : 0.f;
        const int row = quad * 4 + r;
        const int g = 2 * n0 + (l16 >> 3);
        mysH[row * D + (((g ^ row) & 15) << 3) + (l16 & 7)] = f2bf(v);
      }
    }
    #pragma unroll
    for (int kk = 0; kk < 4; ++kk)
      af1[kk] = *(const short8*)&mysH[l16 * D + ((((kk * 4 + quad) ^ l16) & 15) << 3)];
    // ---- layer 2 ----
    #pragma unroll
    for (int n0 = 0; n0 < 8; ++n0) {
      acc0[n0] = (floatx4){0.f, 0.f, 0.f, 0.f};
      acc1[n0] = (floatx4){0.f, 0.f, 0.f, 0.f};
    }
    #pragma unroll
    for (int kk = 0; kk < 4; ++kk) {
      #pragma unroll
      for (int n0 = 0; n0 < 8; ++n0) {
        short8 b = *(const short8*)&sW2[(n0 * 16 + l16) * D + (((kk * 4 + quad) ^ l16) << 3)];
        acc0[n0] = __builtin_amdgcn_mfma_f32_16x16x32_bf16(af0[kk], b, acc0[n0], 0, 0, 0);
        acc1[n0] = __builtin_amdgcn_mfma_f32_16x16x32_bf16(af1[kk], b, acc1[n0], 0, 0, 0);
      }
    }
    // epilogue 2 + store, half 0
    #pragma unroll
    for (int n0 = 0; n0 < 8; ++n0) {
      #pragma unroll
      for (int r = 0; r < 4; ++r) {
        float v = acc0[n0][r] + bias2[n0];
        v = v > 0.f ? v : 0.f;
        const int row = quad * 4 + r;
        const int g = 2 * n0 + (l16 >> 3);
        mysH[row * D + (((g ^ row) & 15) << 3) + (l16 & 7)] = f2bf(v);
      }
    }
    #pragma unroll
    for (int i = 0; i < 4; ++i) {
      const int row = i * 4 + quad;
      short8 vrow = *(const short8*)&mysH[row * D + (((l16 ^ row) & 15) << 3)];
      const int g = mbase + row;
      if (g < nNodes) *(short8*)&h[(size_t)g * D + l16 * 8] = vrow;
    }
    // epilogue 2 + store, half 1
    #pragma unroll
    for (int n0 = 0; n0 < 8; ++n0) {
      #pragma unroll
      for (int r = 0; r < 4; ++r) {
        float v = acc1[n0][r] + bias2[n0];
        v = v > 0.f ? v : 0.f;
        const int row = quad * 4 + r;
        const int g = 2 * n0 + (l16 >> 3);
        mysH[row * D + (((g ^ row) & 15) << 3) + (l16 & 7)] = f2bf(v);
      }
    }
    #pragma unroll
    for (int i = 0; i < 4; ++i) {
      const int row = i * 4 + quad;
      short8 vrow = *(const short8*)&mysH[row * D + (((l16 ^ row) & 15) << 3)];
      const int g = mbase + 16 + row;
      if (g < nNodes) *(short8*)&h[(size_t)g * D + l16 * 8] = vrow;
    }
  }
}

__device__ __forceinline__ float dot2bf(unsigned a, unsigned b, float acc) {
  float a0 = __uint_as_float(a << 16);
  float a1 = __uint_as_float(a & 0xFFFF0000u);
  float b0 = __uint_as_float(b << 16);
  float b1 = __uint_as_float(b & 0xFFFF0000u);
  acc = fmaf(a0, b0, acc);
  acc = fmaf(a1, b1, acc);
  return acc;
}

__device__ __forceinline__ float edge_dot(const uint4& a, const uint4& b) {
  float acc = 0.f;
  acc = dot2bf(a.x, b.x, acc);
  acc = dot2bf(a.y, b.y, acc);
  acc = dot2bf(a.z, b.z, acc);
  acc = dot2bf(a.w, b.w, acc);
  acc += __shfl_xor(acc, 8);
  acc += __shfl_xor(acc, 4);
  acc += __shfl_xor(acc, 2);
  acc += __shfl_xor(acc, 1);
  return acc;
}

// Edge decode: 16 lanes/edge, 8 edges per group -> 16 gathers (256B) in flight.
// One-shot blocks (3907): block churn keeps the load pipe full.
__global__ __launch_bounds__(256) void edge_kernel(
    const unsigned short* __restrict__ h2, const int* __restrict__ eidx,
    float* __restrict__ out, int E) {
  const int sub = threadIdx.x & 15;
  const int grp = (blockIdx.x * 256 + threadIdx.x) >> 4;
  const int e0 = grp * 8;
  if (e0 + 8 <= E) {
    const int4 s0 = *(const int4*)&eidx[e0];
    const int4 s1 = *(const int4*)&eidx[e0 + 4];
    const int4 t0 = *(const int4*)&eidx[E + e0];
    const int4 t1 = *(const int4*)&eidx[E + e0 + 4];
    int s[8] = {s0.x, s0.y, s0.z, s0.w, s1.x, s1.y, s1.z, s1.w};
    int d[8] = {t0.x, t0.y, t0.z, t0.w, t1.x, t1.y, t1.z, t1.w};
    uint4 va[8], vb[8];
    #pragma unroll
    for (int i = 0; i < 8; ++i) {
      va[i] = *(const uint4*)(h2 + (((size_t)(unsigned)s[i]) << 7) + sub * 8);
      vb[i] = *(const uint4*)(h2 + (((size_t)(unsigned)d[i]) << 7) + sub * 8);
    }
    #pragma unroll
    for (int i = 0; i < 8; ++i) {
      float acc = edge_dot(va[i], vb[i]);
      if (sub == 0) out[e0 + i] = acc;
    }
  } else if (e0 < E) {
    for (int e = e0; e < E; ++e) {
      const int s = eidx[e];
      const int d = eidx[E + e];
      const uint4 ua = *(const uint4*)(h2 + (((size_t)(unsigned)s) << 7) + sub * 8);
      const uint4 ub = *(const uint4*)(h2 + (((size_t)(unsigned)d) << 7) + sub * 8);
      float acc = edge_dot(ua, ub);
      if (sub == 0) out[e] = acc;
    }
  }
}

extern "C" void kernel_launch(void* const* d_in, const int* in_sizes, int n_in,
                              void* d_out, int out_size, void* d_ws, size_t ws_size,
                              hipStream_t stream) {
  const float* x  = (const float*)d_in[0];
  const int* eidx = (const int*)d_in[1];
  const int* elab = (const int*)d_in[2];
  const float* W1 = (const float*)d_in[3];
  const float* b1 = (const float*)d_in[4];
  const float* W2 = (const float*)d_in[5];
  const float* b2 = (const float*)d_in[6];
  float* out = (float*)d_out;

  const int nNodes = in_sizes[0] / D;   // 100000
  const int E = in_sizes[2];            // 500000
  const int npairs = (nNodes + 31) / 32;

  unsigned short* h = (unsigned short*)d_ws;  // nNodes*128 bf16 = 25.6 MB

  mlp_fused<<<GRID_MLP, 256, 0, stream>>>(x, W1, b1, W2, b2, h, elab, out,
                                          nNodes, npairs, E);

  const int edgeBlocks = (E + 127) / 128;   // 8 edges per 16-lane group
  edge_kernel<<<edgeBlocks, 256, 0, stream>>>(h, eidx, out, E);
}